// Round 5
// baseline (79.739 us; speedup 1.0000x reference)
//
#include <hip/hip_runtime.h>

// RandomFlipLR: (B=64, C=3, H=512, W=512) fp32, flip W per batch where mask[b]>0.
// Pure memory-bound streaming: 192 MiB in + 192 MiB out, zero reuse.
// - float4 (16B/lane) loads/stores, coalesced
// - flipped source index = idx ^ 127 (128 float4/row, subtract-from-ones == XOR)
// - 8 float4 per thread in contiguous 32KiB/block chunks (best measured config)
// - A/B this round: PLAIN cached loads/stores (no nontemporal) — let L2
//   aggregate/reorder HBM write bursts; nt hints were never isolated.

typedef float f4 __attribute__((ext_vector_type(4)));

#define B_ 64
#define C_ 3
#define H_ 512
#define W_ 512
#define WV (W_ / 4)              // 128 float4 per row
#define PER_B (C_ * H_ * WV)     // 196608 float4 per batch image
#define ITERS 8
#define CHUNK (256 * ITERS)      // 2048 float4 per block = 32 KiB

__global__ __launch_bounds__(256) void RandomFlipLR_71734543777923_kernel(
    const f4* __restrict__ in, const int* __restrict__ mask,
    f4* __restrict__ out) {
    const int b = blockIdx.y;
    const long long base = (long long)b * PER_B;
    const int tid   = threadIdx.x;
    const int chunk = blockIdx.x * CHUNK;

    f4 v[ITERS];
    if (mask[b] > 0) {                        // wave-uniform branch
        #pragma unroll
        for (int i = 0; i < ITERS; ++i) {
            const int idx = chunk + i * 256 + tid;
            f4 t = in[base + (idx ^ (WV - 1))];
            v[i] = t.wzyx;
        }
    } else {
        #pragma unroll
        for (int i = 0; i < ITERS; ++i) {
            const int idx = chunk + i * 256 + tid;
            v[i] = in[base + idx];
        }
    }
    #pragma unroll
    for (int i = 0; i < ITERS; ++i) {
        const int idx = chunk + i * 256 + tid;
        out[base + idx] = v[i];
    }
}

extern "C" void kernel_launch(void* const* d_in, const int* in_sizes, int n_in,
                              void* d_out, int out_size, void* d_ws, size_t ws_size,
                              hipStream_t stream) {
    const f4* in    = (const f4*)d_in[0];
    const int* mask = (const int*)d_in[1];
    f4* out         = (f4*)d_out;

    dim3 block(256);
    dim3 grid(PER_B / CHUNK, B_);            // 96 x 64 = 6144 blocks
    RandomFlipLR_71734543777923_kernel<<<grid, block, 0, stream>>>(in, mask, out);
}

// Round 6
// 67.069 us; speedup vs baseline: 1.1889x; 1.1889x over previous
//
#include <hip/hip_runtime.h>

// RandomFlipLR: (B=64, C=3, H=512, W=512) fp32, flip W per batch where mask[b]>0.
// Pure memory-bound streaming: 192 MiB in + 192 MiB out, zero reuse.
// - float4 (16B/lane) loads/stores, coalesced
// - flipped source index = idx ^ 127 (128 float4/row, subtract-from-ones == XOR)
// - nontemporal REQUIRED: A/B'd in R5, removing nt cost +13% (L2 write-allocate
//   thrash on 384 MiB streamed once)
// - this round: ITERS=4 (16 KiB/block) vs best-so-far ITERS=8 (70.26 us)

typedef float f4 __attribute__((ext_vector_type(4)));

#define B_ 64
#define C_ 3
#define H_ 512
#define W_ 512
#define WV (W_ / 4)              // 128 float4 per row
#define PER_B (C_ * H_ * WV)     // 196608 float4 per batch image
#define ITERS 4
#define CHUNK (256 * ITERS)      // 1024 float4 per block = 16 KiB

__global__ __launch_bounds__(256) void RandomFlipLR_71734543777923_kernel(
    const f4* __restrict__ in, const int* __restrict__ mask,
    f4* __restrict__ out) {
    const int b = blockIdx.y;
    const long long base = (long long)b * PER_B;
    const int tid   = threadIdx.x;
    const int chunk = blockIdx.x * CHUNK;

    f4 v[ITERS];
    if (mask[b] > 0) {                        // wave-uniform branch
        #pragma unroll
        for (int i = 0; i < ITERS; ++i) {
            const int idx = chunk + i * 256 + tid;
            f4 t = __builtin_nontemporal_load(&in[base + (idx ^ (WV - 1))]);
            v[i] = t.wzyx;
        }
    } else {
        #pragma unroll
        for (int i = 0; i < ITERS; ++i) {
            const int idx = chunk + i * 256 + tid;
            v[i] = __builtin_nontemporal_load(&in[base + idx]);
        }
    }
    #pragma unroll
    for (int i = 0; i < ITERS; ++i) {
        const int idx = chunk + i * 256 + tid;
        __builtin_nontemporal_store(v[i], &out[base + idx]);
    }
}

extern "C" void kernel_launch(void* const* d_in, const int* in_sizes, int n_in,
                              void* d_out, int out_size, void* d_ws, size_t ws_size,
                              hipStream_t stream) {
    const f4* in    = (const f4*)d_in[0];
    const int* mask = (const int*)d_in[1];
    f4* out         = (f4*)d_out;

    dim3 block(256);
    dim3 grid(PER_B / CHUNK, B_);            // 192 x 64 = 12288 blocks
    RandomFlipLR_71734543777923_kernel<<<grid, block, 0, stream>>>(in, mask, out);
}

// Round 7
// 65.554 us; speedup vs baseline: 1.2164x; 1.0231x over previous
//
#include <hip/hip_runtime.h>

// RandomFlipLR: (B=64, C=3, H=512, W=512) fp32, flip W per batch where mask[b]>0.
// Pure memory-bound streaming: 192 MiB in + 192 MiB out, zero reuse.
// - float4 (16B/lane) loads/stores, coalesced
// - flipped source index = idx ^ 127 (128 float4/row, subtract-from-ones == XOR)
// - nontemporal REQUIRED: A/B'd in R5, removing nt cost +13% (L2 write-allocate
//   thrash on 384 MiB streamed once)
// - granularity ladder: ITERS 16->74.3us, 8->70.3, 4->67.1; this round ITERS=2

typedef float f4 __attribute__((ext_vector_type(4)));

#define B_ 64
#define C_ 3
#define H_ 512
#define W_ 512
#define WV (W_ / 4)              // 128 float4 per row
#define PER_B (C_ * H_ * WV)     // 196608 float4 per batch image
#define ITERS 2
#define CHUNK (256 * ITERS)      // 512 float4 per block = 8 KiB

__global__ __launch_bounds__(256) void RandomFlipLR_71734543777923_kernel(
    const f4* __restrict__ in, const int* __restrict__ mask,
    f4* __restrict__ out) {
    const int b = blockIdx.y;
    const long long base = (long long)b * PER_B;
    const int tid   = threadIdx.x;
    const int chunk = blockIdx.x * CHUNK;

    f4 v[ITERS];
    if (mask[b] > 0) {                        // wave-uniform branch
        #pragma unroll
        for (int i = 0; i < ITERS; ++i) {
            const int idx = chunk + i * 256 + tid;
            f4 t = __builtin_nontemporal_load(&in[base + (idx ^ (WV - 1))]);
            v[i] = t.wzyx;
        }
    } else {
        #pragma unroll
        for (int i = 0; i < ITERS; ++i) {
            const int idx = chunk + i * 256 + tid;
            v[i] = __builtin_nontemporal_load(&in[base + idx]);
        }
    }
    #pragma unroll
    for (int i = 0; i < ITERS; ++i) {
        const int idx = chunk + i * 256 + tid;
        __builtin_nontemporal_store(v[i], &out[base + idx]);
    }
}

extern "C" void kernel_launch(void* const* d_in, const int* in_sizes, int n_in,
                              void* d_out, int out_size, void* d_ws, size_t ws_size,
                              hipStream_t stream) {
    const f4* in    = (const f4*)d_in[0];
    const int* mask = (const int*)d_in[1];
    f4* out         = (f4*)d_out;

    dim3 block(256);
    dim3 grid(PER_B / CHUNK, B_);            // 384 x 64 = 24576 blocks
    RandomFlipLR_71734543777923_kernel<<<grid, block, 0, stream>>>(in, mask, out);
}

// Round 8
// 65.122 us; speedup vs baseline: 1.2245x; 1.0066x over previous
//
#include <hip/hip_runtime.h>

// RandomFlipLR: (B=64, C=3, H=512, W=512) fp32, flip W per batch where mask[b]>0.
// Pure memory-bound streaming: 192 MiB in + 192 MiB out, zero reuse.
// - float4 (16B/lane) loads/stores, coalesced
// - flipped source index = idx ^ 127 (128 float4/row, subtract-from-ones == XOR)
// - nontemporal REQUIRED: A/B'd in R5, removing nt cost +13% (L2 write-allocate
//   thrash on 384 MiB streamed once)
// - granularity ladder: ITERS 16->74.3us, 8->70.3, 4->67.1, 2->65.55;
//   this round ITERS=1 (finest granularity, one f4 per thread)

typedef float f4 __attribute__((ext_vector_type(4)));

#define B_ 64
#define C_ 3
#define H_ 512
#define W_ 512
#define WV (W_ / 4)              // 128 float4 per row
#define PER_B (C_ * H_ * WV)     // 196608 float4 per batch image

__global__ __launch_bounds__(256) void RandomFlipLR_71734543777923_kernel(
    const f4* __restrict__ in, const int* __restrict__ mask,
    f4* __restrict__ out) {
    const int b = blockIdx.y;
    const long long base = (long long)b * PER_B;
    const int idx = blockIdx.x * 256 + threadIdx.x;

    if (mask[b] > 0) {                        // wave-uniform branch
        f4 t = __builtin_nontemporal_load(&in[base + (idx ^ (WV - 1))]);
        __builtin_nontemporal_store(t.wzyx, &out[base + idx]);
    } else {
        f4 t = __builtin_nontemporal_load(&in[base + idx]);
        __builtin_nontemporal_store(t, &out[base + idx]);
    }
}

extern "C" void kernel_launch(void* const* d_in, const int* in_sizes, int n_in,
                              void* d_out, int out_size, void* d_ws, size_t ws_size,
                              hipStream_t stream) {
    const f4* in    = (const f4*)d_in[0];
    const int* mask = (const int*)d_in[1];
    f4* out         = (f4*)d_out;

    dim3 block(256);
    dim3 grid(PER_B / 256, B_);              // 768 x 64 = 49152 blocks
    RandomFlipLR_71734543777923_kernel<<<grid, block, 0, stream>>>(in, mask, out);
}